// Round 4
// baseline (353.725 us; speedup 1.0000x reference)
//
#include <hip/hip_runtime.h>
#include <hip/hip_cooperative_groups.h>
#include <hip/hip_fp16.h>
#include <math.h>

#define FDIM  128
#define L1OUT 16
#define L2DIM 17
#define TRM   128     // f-rows per block in node_transform

namespace cg = cooperative_groups;

typedef _Float16 f16x8 __attribute__((ext_vector_type(8)));   // MFMA A/B frag (4 VGPR)
typedef float    f32x4 __attribute__((ext_vector_type(4)));   // MFMA C/D frag

// one 32-byte fp16 node row (16 halves); align 16 -> 2x global_load_dwordx4
struct __align__(16) H16 { __half2 h[8]; };

__device__ __forceinline__ float lrelu(float v) { return v >= 0.f ? v : 0.1f * v; }

// ============================================================================
// K1 (MFMA, direct-load): [A|B] = f @ W'. R3 insight: the old LDS staging had
// ZERO cross-wave reuse (each f-row consumed by exactly one wave) -> the
// global->LDS->frag round-trip + barrier bought nothing and the 34.8KB tile
// capped occupancy at 4 blocks/CU (measured Occ 26%, VALU 2.4%: latency-bound
// with everything idle). Now each lane loads its A-frag directly from global
// (2x float4 of its own row; per wave & ks that's 16 rows x 128B contiguous;
// f is L3-resident per the 28MB FETCH vs 51MB f). No LDS, no barrier,
// __launch_bounds__(256,6) -> ~24 waves/CU for latency hiding.
// Layouts (HW-verified per guide): A-frag A[m=lane&15][k=(lane>>4)*8+j];
// B-frag B[k=(lane>>4)*8+j][n=lane&15]; C/D col=lane&15, row=(lane>>4)*4+reg.
// + degree atomics folded in (deg zeroed by memsetAsync before this kernel).
// ============================================================================
__global__ __launch_bounds__(256, 6) void node_transform(
    const float* __restrict__ f, const float* __restrict__ W1,
    const float* __restrict__ b1,
    const int* __restrict__ ind_i, const float* __restrict__ val,
    H16* __restrict__ A, H16* __restrict__ B,
    float* __restrict__ deg, int N, int E)
{
    const int t    = threadIdx.x;
    const int gtid = blockIdx.x * 256 + t;
    const int GT   = gridDim.x * 256;

    // ---- degree atomics (4 edges/thread, grid-stride, fire-and-forget) ----
    {
        const int E4 = E >> 2;
        for (int q = gtid; q < E4; q += GT) {
            int e = q << 2;
            int4   ii = *reinterpret_cast<const int4*>(ind_i + e);
            float4 vv = *reinterpret_cast<const float4*>(val + e);
            atomicAdd(&deg[ii.x], fabsf(vv.x));
            atomicAdd(&deg[ii.y], fabsf(vv.y));
            atomicAdd(&deg[ii.z], fabsf(vv.z));
            atomicAdd(&deg[ii.w], fabsf(vv.w));
        }
        if (gtid < (E & 3)) {
            int e = (E & ~3) + gtid;
            atomicAdd(&deg[ind_i[e]], fabsf(val[e]));
        }
    }

    const int lane = t & 63;
    const int wv   = t >> 6;          // wave 0..3
    const int n    = lane & 15;       // MFMA matrix-dim index (col)
    const int quad = lane >> 4;       // k-block / row-group selector

    // ---- load W' B-frags once per block: bfr[nt][ks], k = 32*ks + 8*quad + j
    f16x8 bfr[2][4];
#pragma unroll
    for (int nt = 0; nt < 2; ++nt)
#pragma unroll
        for (int ks = 0; ks < 4; ++ks) {
            f16x8 bf;
#pragma unroll
            for (int j = 0; j < 8; ++j) {
                int k = 32 * ks + 8 * quad + j;
                bf[j] = (_Float16)W1[(size_t)(nt * FDIM + k) * L1OUT + n];
            }
            bfr[nt][ks] = bf;
        }
    float b1v = b1[n];                // folded into nt=0 accumulator init

    const int base = blockIdx.x * TRM;

    // ---- compute: wave wv handles M-subtiles wv and wv+4 (16 rows each) ----
#pragma unroll
    for (int si = 0; si < 2; ++si) {
        const int m0 = (wv + 4 * si) * 16;
        int row = base + m0 + n;
        if (row > N - 1) row = N - 1;             // clamp: safe OOB reads
        const float* fr = f + (size_t)row * FDIM;

        f32x4 acc0 = { b1v, b1v, b1v, b1v };      // A-cols + b1
        f32x4 acc1 = { 0.f, 0.f, 0.f, 0.f };      // B-cols
#pragma unroll
        for (int ks = 0; ks < 4; ++ks) {
            const float4* p = reinterpret_cast<const float4*>(fr + 32 * ks + 8 * quad);
            float4 lo = p[0];
            float4 hi = p[1];
            f16x8 af;
            af[0] = (_Float16)lo.x; af[1] = (_Float16)lo.y;
            af[2] = (_Float16)lo.z; af[3] = (_Float16)lo.w;
            af[4] = (_Float16)hi.x; af[5] = (_Float16)hi.y;
            af[6] = (_Float16)hi.z; af[7] = (_Float16)hi.w;
            acc0 = __builtin_amdgcn_mfma_f32_16x16x32_f16(af, bfr[0][ks], acc0, 0, 0, 0);
            acc1 = __builtin_amdgcn_mfma_f32_16x16x32_f16(af, bfr[1][ks], acc1, 0, 0, 0);
        }
        // epilogue: D col = n, rows = m0 + quad*4 + reg
#pragma unroll
        for (int reg = 0; reg < 4; ++reg) {
            int node = base + m0 + quad * 4 + reg;
            if (node < N) {
                reinterpret_cast<_Float16*>(A + node)[n] = (_Float16)acc0[reg];
                reinterpret_cast<_Float16*>(B + node)[n] = (_Float16)acc1[reg];
            }
        }
    }
}

// ============================================================================
// Shared MLP tail: x[17] -> L2 layer -> collapse -> exp. NO references/structs
// in the hot path (R1 lesson: addressable gather results -> alloca -> 672 MB
// scratch traffic). All indices compile-time; SROA keeps everything in VGPRs.
// ============================================================================
#define MLP_TAIL(X, EXOUT)                                                  \
    {                                                                       \
        float acc[L2DIM];                                                   \
        _Pragma("unroll")                                                   \
        for (int r = 0; r < L2DIM; ++r) acc[r] = b2s[r];                    \
        _Pragma("unroll")                                                   \
        for (int c = 0; c < L2DIM; ++c) {                                   \
            float xc = X[c];                                                \
            const float4* r4 = reinterpret_cast<const float4*>(&w2s[c * 20]); \
            float4 w0 = r4[0], w1v = r4[1], w2v = r4[2], w3 = r4[3];        \
            float  w16 = w2s[c * 20 + 16];                                  \
            acc[0]  += xc * w0.x;  acc[1]  += xc * w0.y;                    \
            acc[2]  += xc * w0.z;  acc[3]  += xc * w0.w;                    \
            acc[4]  += xc * w1v.x; acc[5]  += xc * w1v.y;                   \
            acc[6]  += xc * w1v.z; acc[7]  += xc * w1v.w;                   \
            acc[8]  += xc * w2v.x; acc[9]  += xc * w2v.y;                   \
            acc[10] += xc * w2v.z; acc[11] += xc * w2v.w;                   \
            acc[12] += xc * w3.x;  acc[13] += xc * w3.y;                    \
            acc[14] += xc * w3.z;  acc[15] += xc * w3.w;                    \
            acc[16] += xc * w16;                                            \
        }                                                                   \
        float ev = bc0s;                                                    \
        _Pragma("unroll")                                                   \
        for (int r = 0; r < L2DIM; ++r) ev += lrelu(acc[r]) * wcs[r];       \
        EXOUT = __expf(ev);                                                 \
    }

#define EDGE_X(X, ALO, AHI, BLO, BHI, V, D)                                 \
    _Pragma("unroll")                                                       \
    for (int k = 0; k < 8; ++k) {                                           \
        X[k]     = lrelu((float)ALO[k] + (float)BLO[k]);                    \
        X[k + 8] = lrelu((float)AHI[k] + (float)BHI[k]);                    \
    }                                                                       \
    X[L1OUT] = fabsf(V) / D;

// ============================================================================
// K2+K3 FUSED (cooperative): per-edge MLP -> exp -> ssum atomics ->
// grid.sync() -> coherent ssum gather -> divide -> coalesced final store.
// R3 lesson: absmax was exactly 1.0 = output never written = the cooperative
// ENQUEUE failed (return code was discarded). Now the host checks the return
// and falls back to the proven split kernels in-stream -> correctness is
// path-independent. Phase-2 ssum reads use device-scope atomic loads to rule
// out XCD-L2 staleness after grid.sync().
// ============================================================================
__global__ __launch_bounds__(256, 4) void edge_mlp_norm(
    const int* __restrict__ ind, const float* __restrict__ val,
    const H16* __restrict__ A, const H16* __restrict__ B,
    const float* __restrict__ deg,
    const float* __restrict__ W2, const float* __restrict__ b2,
    const float* __restrict__ Wc, const float* __restrict__ bc,
    float* __restrict__ out, float* __restrict__ ssum, int E, int NT)
{
    __shared__ float w2s[L2DIM * 20];   // row c at w2s[c*20], 16B-aligned
    __shared__ float b2s[L2DIM];
    __shared__ float wcs[L2DIM];
    __shared__ float bc0s;

    const int t = threadIdx.x;
    for (int idx = t; idx < L2DIM * L2DIM; idx += 256) {
        int c = idx / L2DIM, r = idx - c * L2DIM;
        w2s[c * 20 + r] = W2[idx];
    }
    if (t < L2DIM) b2s[t] = b2[t];
    if (t < L2DIM) wcs[t] = Wc[t];
    if (t == 0)    bc0s   = bc[0];
    __syncthreads();

    const int tid = blockIdx.x * 256 + t;
    const int Em  = E - 1;
    const int e0 = tid, e1 = tid + NT, e2 = tid + 2 * NT, e3 = tid + 3 * NT;
    const bool h0 = e0 < E, h1 = e1 < E, h2 = e2 < E, h3 = e3 < E;
    const int s0 = h0 ? e0 : Em, s1 = h1 ? e1 : Em,
              s2 = h2 ? e2 : Em, s3 = h3 ? e3 : Em;   // clamped (safe) addrs

    int   i0, i1, i2, i3;
    float ex0 = 0.f, ex1 = 0.f, ex2 = 0.f, ex3 = 0.f;

    // ---- pair {0,1}: both edges' full load pipeline issued up front ----
    i0 = ind[s0];  int j0 = ind[E + s0];
    i1 = ind[s1];  int j1 = ind[E + s1];
    {
        const f16x8* pA0 = reinterpret_cast<const f16x8*>(A + i0);
        const f16x8* pB0 = reinterpret_cast<const f16x8*>(B + j0);
        const f16x8* pA1 = reinterpret_cast<const f16x8*>(A + i1);
        const f16x8* pB1 = reinterpret_cast<const f16x8*>(B + j1);
        f16x8 a0lo = pA0[0], a0hi = pA0[1];
        f16x8 b0lo = pB0[0], b0hi = pB0[1];
        float v0   = val[s0];
        float d0   = deg[i0];
        f16x8 a1lo = pA1[0], a1hi = pA1[1];   // in flight under edge-0 MLP
        f16x8 b1lo = pB1[0], b1hi = pB1[1];
        float v1   = val[s1];
        float d1   = deg[i1];
        {
            float x[L2DIM];
            EDGE_X(x, a0lo, a0hi, b0lo, b0hi, v0, d0);
            MLP_TAIL(x, ex0);
        }
        if (h0) atomicAdd(&ssum[i0], ex0);
        {
            float x[L2DIM];
            EDGE_X(x, a1lo, a1hi, b1lo, b1hi, v1, d1);
            MLP_TAIL(x, ex1);
        }
        if (h1) atomicAdd(&ssum[i1], ex1);
    }

    // ---- pair {2,3} ----
    i2 = ind[s2];  int j2 = ind[E + s2];
    i3 = ind[s3];  int j3 = ind[E + s3];
    {
        const f16x8* pA2 = reinterpret_cast<const f16x8*>(A + i2);
        const f16x8* pB2 = reinterpret_cast<const f16x8*>(B + j2);
        const f16x8* pA3 = reinterpret_cast<const f16x8*>(A + i3);
        const f16x8* pB3 = reinterpret_cast<const f16x8*>(B + j3);
        f16x8 a2lo = pA2[0], a2hi = pA2[1];
        f16x8 b2lo = pB2[0], b2hi = pB2[1];
        float v2   = val[s2];
        float d2   = deg[i2];
        f16x8 a3lo = pA3[0], a3hi = pA3[1];
        f16x8 b3lo = pB3[0], b3hi = pB3[1];
        float v3   = val[s3];
        float d3   = deg[i3];
        {
            float x[L2DIM];
            EDGE_X(x, a2lo, a2hi, b2lo, b2hi, v2, d2);
            MLP_TAIL(x, ex2);
        }
        if (h2) atomicAdd(&ssum[i2], ex2);
        {
            float x[L2DIM];
            EDGE_X(x, a3lo, a3hi, b3lo, b3hi, v3, d3);
            MLP_TAIL(x, ex3);
        }
        if (h3) atomicAdd(&ssum[i3], ex3);
    }

    // ---- all ssum atomics complete grid-wide ----
    cg::this_grid().sync();

    // ---- phase 2: coherent denominator gathers (device scope), store ----
    float S0 = __hip_atomic_load(&ssum[i0], __ATOMIC_RELAXED, __HIP_MEMORY_SCOPE_AGENT);
    float S1 = __hip_atomic_load(&ssum[i1], __ATOMIC_RELAXED, __HIP_MEMORY_SCOPE_AGENT);
    float S2 = __hip_atomic_load(&ssum[i2], __ATOMIC_RELAXED, __HIP_MEMORY_SCOPE_AGENT);
    float S3 = __hip_atomic_load(&ssum[i3], __ATOMIC_RELAXED, __HIP_MEMORY_SCOPE_AGENT);
    if (h0) out[e0] = ex0 / S0;
    if (h1) out[e1] = ex1 / S1;
    if (h2) out[e2] = ex2 / S2;
    if (h3) out[e3] = ex3 / S3;
}

// ============================================================================
// Fallback split kernels (R2-proven, 209.6us path): used when the cooperative
// enqueue is rejected (co-residency validation, graph capture, etc.).
// ============================================================================
__global__ __launch_bounds__(256, 4) void edge_mlp(
    const int* __restrict__ ind, const float* __restrict__ val,
    const H16* __restrict__ A, const H16* __restrict__ B,
    const float* __restrict__ deg,
    const float* __restrict__ W2, const float* __restrict__ b2,
    const float* __restrict__ Wc, const float* __restrict__ bc,
    float* __restrict__ eout, float* __restrict__ ssum, int E)
{
    __shared__ float w2s[L2DIM * 20];
    __shared__ float b2s[L2DIM];
    __shared__ float wcs[L2DIM];
    __shared__ float bc0s;

    const int t = threadIdx.x;
    for (int idx = t; idx < L2DIM * L2DIM; idx += 256) {
        int c = idx / L2DIM, r = idx - c * L2DIM;
        w2s[c * 20 + r] = W2[idx];
    }
    if (t < L2DIM) b2s[t] = b2[t];
    if (t < L2DIM) wcs[t] = Wc[t];
    if (t == 0)    bc0s   = bc[0];
    __syncthreads();

    const int E2 = (E + 1) >> 1;
    const int p  = blockIdx.x * 256 + t;
    if (p >= E2) return;

    const int  e0   = p;
    const int  e1   = p + E2;
    const bool has1 = (e1 < E);
    const int  e1s  = has1 ? e1 : e0;

    int i0 = ind[e0];   int j0 = ind[E + e0];
    int i1 = ind[e1s];  int j1 = ind[E + e1s];

    const f16x8* pA0 = reinterpret_cast<const f16x8*>(A + i0);
    const f16x8* pB0 = reinterpret_cast<const f16x8*>(B + j0);
    const f16x8* pA1 = reinterpret_cast<const f16x8*>(A + i1);
    const f16x8* pB1 = reinterpret_cast<const f16x8*>(B + j1);

    f16x8 a0lo = pA0[0], a0hi = pA0[1];
    f16x8 b0lo = pB0[0], b0hi = pB0[1];
    float v0   = val[e0];
    float d0   = deg[i0];
    f16x8 a1lo = pA1[0], a1hi = pA1[1];
    f16x8 b1lo = pB1[0], b1hi = pB1[1];
    float v1   = val[e1s];
    float d1   = deg[i1];

    {
        float x[L2DIM];
        EDGE_X(x, a0lo, a0hi, b0lo, b0hi, v0, d0);
        float ex0;
        MLP_TAIL(x, ex0);
        eout[e0] = ex0;
        atomicAdd(&ssum[i0], ex0);
    }
    if (has1) {
        float x[L2DIM];
        EDGE_X(x, a1lo, a1hi, b1lo, b1hi, v1, d1);
        float ex1;
        MLP_TAIL(x, ex1);
        eout[e1] = ex1;
        atomicAdd(&ssum[i1], ex1);
    }
}

__global__ void normalize(const int* __restrict__ ind_i, const float* __restrict__ ssum,
                          float* __restrict__ ex, int E) {
    int t = blockIdx.x * blockDim.x + threadIdx.x;
    int e = t * 4;
    if (e + 3 < E) {
        int4   ii = *reinterpret_cast<const int4*>(ind_i + e);
        float4 vv = *reinterpret_cast<const float4*>(ex + e);
        vv.x /= ssum[ii.x];
        vv.y /= ssum[ii.y];
        vv.z /= ssum[ii.z];
        vv.w /= ssum[ii.w];
        *reinterpret_cast<float4*>(ex + e) = vv;
    } else {
        for (; e < E; ++e) ex[e] = ex[e] / ssum[ind_i[e]];
    }
}

extern "C" void kernel_launch(void* const* d_in, const int* in_sizes, int n_in,
                              void* d_out, int out_size, void* d_ws, size_t ws_size,
                              hipStream_t stream) {
    const int*   Jt_ind = (const int*)  d_in[0];   // [2,E]
    const float* Jt_val = (const float*)d_in[1];   // [E]
    const float* f      = (const float*)d_in[2];   // [N,128]
    const float* W1 = (const float*)d_in[4];       // [256,16]
    const float* b1 = (const float*)d_in[5];       // [16]
    const float* W2 = (const float*)d_in[6];       // [17,17]
    const float* b2 = (const float*)d_in[7];       // [17]
    const float* Wc = (const float*)d_in[8];       // [17,1]
    const float* bc = (const float*)d_in[9];       // [1]

    const int E = in_sizes[1];
    const int N = in_sizes[2] / FDIM;
    float* out = (float*)d_out;                    // [E] fp32

    // workspace: deg[N] | ssum[N] (contiguous -> one memset) | A[N] | B[N]
    char* ws = (char*)d_ws;
    float* deg  = (float*)ws;  ws += (size_t)N * sizeof(float);
    float* ssum = (float*)ws;  ws += (size_t)N * sizeof(float);
    H16*   A    = (H16*)ws;    ws += (size_t)N * sizeof(H16);
    H16*   Bm   = (H16*)ws;    ws += (size_t)N * sizeof(H16);

    const int B256 = 256;
    const int nblk = (N + TRM - 1) / TRM;                   // node tiles (128 rows)

    hipMemsetAsync(deg, 0, 2 * (size_t)N * sizeof(float), stream);
    node_transform<<<nblk, B256, 0, stream>>>(f, W1, b1, Jt_ind, Jt_val,
                                              A, Bm, deg, N, E);

    hipError_t cerr = hipErrorUnknown;
    int cblk = (E + 4 * B256 - 1) / (4 * B256);             // 4 edges/thread
    if (cblk < 1) cblk = 1;
    if (cblk <= 1024) {
        // cooperative fused path: grid <= 1024 blocks, co-resident via
        // __launch_bounds__(256,4). Enqueue return code checked!
        int NT = cblk * B256;
        const int*   ind_a  = Jt_ind;
        const float* val_a  = Jt_val;
        const H16*   A_a    = A;
        const H16*   B_a    = Bm;
        const float* deg_a  = deg;
        float*       out_a  = out;
        float*       ssum_a = ssum;
        int          E_a    = E;
        int          NT_a   = NT;
        void* args[] = { (void*)&ind_a, (void*)&val_a, (void*)&A_a, (void*)&B_a,
                         (void*)&deg_a, (void*)&W2, (void*)&b2, (void*)&Wc,
                         (void*)&bc, (void*)&out_a, (void*)&ssum_a,
                         (void*)&E_a, (void*)&NT_a };
        cerr = hipLaunchCooperativeKernel((void*)edge_mlp_norm, dim3(cblk),
                                          dim3(B256), args, 0, stream);
    }
    if (cerr != hipSuccess) {
        // proven split path
        const int E2   = (E + 1) / 2;
        const int eblk = (E2 + B256 - 1) / B256;
        const int qblk = ((E + 3) / 4 + B256 - 1) / B256;
        edge_mlp <<<eblk, B256, 0, stream>>>(Jt_ind, Jt_val, A, Bm, deg,
                                             W2, b2, Wc, bc, out, ssum, E);
        normalize<<<qblk, B256, 0, stream>>>(Jt_ind, ssum, out, E);
    }
}

// Round 5
// 209.710 us; speedup vs baseline: 1.6867x; 1.6867x over previous
//
#include <hip/hip_runtime.h>
#include <hip/hip_fp16.h>
#include <math.h>

#define FDIM  128
#define L1OUT 16
#define L2DIM 17
#define TRM   128     // f-rows per block in node_transform (MFMA version)
#define HSTR  136     // LDS tile row stride in halves (272 B: 2-way-only conflicts)

typedef _Float16 f16x8 __attribute__((ext_vector_type(8)));   // MFMA A/B frag (4 VGPR)
typedef float    f32x4 __attribute__((ext_vector_type(4)));   // MFMA C/D frag

// one 32-byte fp16 node row (16 halves); align 16 -> 2x global_load_dwordx4
struct __align__(16) H16 { __half2 h[8]; };

__device__ __forceinline__ float lrelu(float v) { return v >= 0.f ? v : 0.1f * v; }

// ============================================================================
// K1 (MFMA, LDS-staged): [A|B] = f @ W'. R2-proven version, reverted from the
// R4 direct-load experiment (confounded with cooperative-launch overhead; R4
// total arithmetic suggested the direct version may be ~tens of us SLOWER --
// revert to the measured-good variant, re-attack K1 only once its warm cost
// is actually visible in the trace).
// R4 lesson (permanent): cooperative grid.sync fusion is structurally wrong
// here -- device-scope release/acquire on non-coherent per-XCD L2s pushed
// ssum traffic to HBM (FETCH +27MB, WRITE +45MB) and the whole grid stalled
// on stragglers: fused K2+K3 = 176us vs 58+12 split. Deleted.
// Layouts (HW-verified per guide): A-frag A[m=lane&15][k=(lane>>4)*8+j];
// B-frag B[k=(lane>>4)*8+j][n=lane&15]; C/D col=lane&15, row=(lane>>4)*4+reg.
// + degree atomics folded in (deg zeroed by memsetAsync before this kernel).
// ============================================================================
__global__ void node_transform(
    const float* __restrict__ f, const float* __restrict__ W1,
    const float* __restrict__ b1,
    const int* __restrict__ ind_i, const float* __restrict__ val,
    H16* __restrict__ A, H16* __restrict__ B,
    float* __restrict__ deg, int N, int E)
{
    __shared__ __align__(16) _Float16 tile[TRM * HSTR];   // 34.8 KB

    const int t    = threadIdx.x;
    const int gtid = blockIdx.x * 256 + t;
    const int GT   = gridDim.x * 256;

    // ---- degree atomics (4 edges/thread, grid-stride, fire-and-forget) ----
    {
        const int E4 = E >> 2;
        for (int q = gtid; q < E4; q += GT) {
            int e = q << 2;
            int4   ii = *reinterpret_cast<const int4*>(ind_i + e);
            float4 vv = *reinterpret_cast<const float4*>(val + e);
            atomicAdd(&deg[ii.x], fabsf(vv.x));
            atomicAdd(&deg[ii.y], fabsf(vv.y));
            atomicAdd(&deg[ii.z], fabsf(vv.z));
            atomicAdd(&deg[ii.w], fabsf(vv.w));
        }
        if (gtid < (E & 3)) {
            int e = (E & ~3) + gtid;
            atomicAdd(&deg[ind_i[e]], fabsf(val[e]));
        }
    }

    const int lane = t & 63;
    const int wv   = t >> 6;          // wave 0..3
    const int n    = lane & 15;       // MFMA matrix-dim index (col)
    const int quad = lane >> 4;       // k-block / row-group selector

    // ---- load W' B-frags once per block: bfr[nt][ks], k = 32*ks + 8*quad + j
    f16x8 bfr[2][4];
#pragma unroll
    for (int nt = 0; nt < 2; ++nt)
#pragma unroll
        for (int ks = 0; ks < 4; ++ks) {
            f16x8 bf;
#pragma unroll
            for (int j = 0; j < 8; ++j) {
                int k = 32 * ks + 8 * quad + j;
                bf[j] = (_Float16)W1[(size_t)(nt * FDIM + k) * L1OUT + n];
            }
            bfr[nt][ks] = bf;
        }
    float b1v = b1[n];                // folded into nt=0 accumulator init

    // ---- stage 128 f-rows as fp16 into padded LDS tile (coalesced) ----
    const int base = blockIdx.x * TRM;
#pragma unroll
    for (int q = 0; q < 8; ++q) {
        int p  = t + 256 * q;         // half8-chunk index 0..2047
        int r  = p >> 4;              // 16 chunks per row
        int c8 = p & 15;              // chunk within row (8 halves)
        float4 lo = make_float4(0.f, 0.f, 0.f, 0.f);
        float4 hi = lo;
        if (base + r < N) {
            const float4* src = reinterpret_cast<const float4*>(
                f + (size_t)(base + r) * FDIM + c8 * 8);
            lo = src[0];
            hi = src[1];
        }
        f16x8 hx;
        hx[0] = (_Float16)lo.x; hx[1] = (_Float16)lo.y;
        hx[2] = (_Float16)lo.z; hx[3] = (_Float16)lo.w;
        hx[4] = (_Float16)hi.x; hx[5] = (_Float16)hi.y;
        hx[6] = (_Float16)hi.z; hx[7] = (_Float16)hi.w;
        *reinterpret_cast<f16x8*>(&tile[r * HSTR + c8 * 8]) = hx;
    }
    __syncthreads();

    // ---- compute: wave wv handles M-subtiles wv and wv+4 (16 rows each) ----
#pragma unroll
    for (int si = 0; si < 2; ++si) {
        const int m0 = (wv + 4 * si) * 16;
        f32x4 acc0 = { b1v, b1v, b1v, b1v };      // A-cols + b1
        f32x4 acc1 = { 0.f, 0.f, 0.f, 0.f };      // B-cols
#pragma unroll
        for (int ks = 0; ks < 4; ++ks) {
            // A-frag: row m0+n, k = 32*ks + 8*quad .. +7  (one ds_read_b128)
            f16x8 af = *reinterpret_cast<const f16x8*>(
                &tile[(m0 + n) * HSTR + 32 * ks + 8 * quad]);
            acc0 = __builtin_amdgcn_mfma_f32_16x16x32_f16(af, bfr[0][ks], acc0, 0, 0, 0);
            acc1 = __builtin_amdgcn_mfma_f32_16x16x32_f16(af, bfr[1][ks], acc1, 0, 0, 0);
        }
        // epilogue: D col = n, rows = m0 + quad*4 + reg
#pragma unroll
        for (int reg = 0; reg < 4; ++reg) {
            int node = base + m0 + quad * 4 + reg;
            if (node < N) {
                reinterpret_cast<_Float16*>(A + node)[n] = (_Float16)acc0[reg];
                reinterpret_cast<_Float16*>(B + node)[n] = (_Float16)acc1[reg];
            }
        }
    }
}

// ============================================================================
// Shared MLP tail: x[17] -> L2 layer -> collapse -> exp. NO references/structs
// in the hot path (R1 lesson: addressable gather results -> alloca -> 672 MB
// scratch traffic). All indices compile-time; SROA keeps everything in VGPRs.
// ============================================================================
#define MLP_TAIL(X, EXOUT)                                                  \
    {                                                                       \
        float acc[L2DIM];                                                   \
        _Pragma("unroll")                                                   \
        for (int r = 0; r < L2DIM; ++r) acc[r] = b2s[r];                    \
        _Pragma("unroll")                                                   \
        for (int c = 0; c < L2DIM; ++c) {                                   \
            float xc = X[c];                                                \
            const float4* r4 = reinterpret_cast<const float4*>(&w2s[c * 20]); \
            float4 w0 = r4[0], w1v = r4[1], w2v = r4[2], w3 = r4[3];        \
            float  w16 = w2s[c * 20 + 16];                                  \
            acc[0]  += xc * w0.x;  acc[1]  += xc * w0.y;                    \
            acc[2]  += xc * w0.z;  acc[3]  += xc * w0.w;                    \
            acc[4]  += xc * w1v.x; acc[5]  += xc * w1v.y;                   \
            acc[6]  += xc * w1v.z; acc[7]  += xc * w1v.w;                   \
            acc[8]  += xc * w2v.x; acc[9]  += xc * w2v.y;                   \
            acc[10] += xc * w2v.z; acc[11] += xc * w2v.w;                   \
            acc[12] += xc * w3.x;  acc[13] += xc * w3.y;                    \
            acc[14] += xc * w3.z;  acc[15] += xc * w3.w;                    \
            acc[16] += xc * w16;                                            \
        }                                                                   \
        float ev = bc0s;                                                    \
        _Pragma("unroll")                                                   \
        for (int r = 0; r < L2DIM; ++r) ev += lrelu(acc[r]) * wcs[r];       \
        EXOUT = __expf(ev);                                                 \
    }

#define EDGE_X(X, ALO, AHI, BLO, BHI, V, D)                                 \
    _Pragma("unroll")                                                       \
    for (int k = 0; k < 8; ++k) {                                           \
        X[k]     = lrelu((float)ALO[k] + (float)BLO[k]);                    \
        X[k + 8] = lrelu((float)AHI[k] + (float)BHI[k]);                    \
    }                                                                       \
    X[L1OUT] = fabsf(V) / D;

// ============================================================================
// K2: per-edge MLP -> exp -> segment-sum. TWO edges per thread (e, e+E/2).
// R2 finding: with plain source order the compiler SANK edge-1's gathers
// below edge-0's compute (VGPR stayed 64 -- two edges' operands cannot fit),
// so the R0 prefetch theory was never actually executed. Fix (this round):
// __builtin_amdgcn_sched_barrier(0) pins ALL 12+ loads before any compute --
// edge-1's random gathers stay in flight (vmcnt>0) under edge-0's ~370-instr
// MLP. Expected: VGPR ~90-110; if it stays 64 the lever is dead.
// R1 lesson: no references/structs/lambdas on gather results (alloca ->
// scratch). Weights in LDS (stride-20 rows). Softmax max-pass removed:
// identical ratios; |e_val| <~ 15 (fp32-safe).
// ============================================================================
__global__ __launch_bounds__(256, 4) void edge_mlp(
    const int* __restrict__ ind, const float* __restrict__ val,
    const H16* __restrict__ A, const H16* __restrict__ B,
    const float* __restrict__ deg,
    const float* __restrict__ W2, const float* __restrict__ b2,
    const float* __restrict__ Wc, const float* __restrict__ bc,
    float* __restrict__ eout, float* __restrict__ ssum, int E)
{
    __shared__ float w2s[L2DIM * 20];   // row c at w2s[c*20], 16B-aligned
    __shared__ float b2s[L2DIM];
    __shared__ float wcs[L2DIM];
    __shared__ float bc0s;

    const int t = threadIdx.x;
    for (int idx = t; idx < L2DIM * L2DIM; idx += 256) {
        int c = idx / L2DIM, r = idx - c * L2DIM;
        w2s[c * 20 + r] = W2[idx];
    }
    if (t < L2DIM) b2s[t] = b2[t];
    if (t < L2DIM) wcs[t] = Wc[t];
    if (t == 0)    bc0s   = bc[0];
    __syncthreads();

    const int E2 = (E + 1) >> 1;          // pair stride
    const int p  = blockIdx.x * 256 + t;
    if (p >= E2) return;

    const int  e0   = p;
    const int  e1   = p + E2;
    const bool has1 = (e1 < E);
    const int  e1s  = has1 ? e1 : e0;     // safe clone address for tail

    // ---- issue the full load pipeline for both edges up front ----
    int i0 = ind[e0];   int j0 = ind[E + e0];
    int i1 = ind[e1s];  int j1 = ind[E + e1s];

    const f16x8* pA0 = reinterpret_cast<const f16x8*>(A + i0);
    const f16x8* pB0 = reinterpret_cast<const f16x8*>(B + j0);
    const f16x8* pA1 = reinterpret_cast<const f16x8*>(A + i1);
    const f16x8* pB1 = reinterpret_cast<const f16x8*>(B + j1);

    f16x8 a0lo = pA0[0], a0hi = pA0[1];   // 2x global_load_dwordx4 each
    f16x8 b0lo = pB0[0], b0hi = pB0[1];
    float v0   = val[e0];
    float d0   = deg[i0];
    f16x8 a1lo = pA1[0], a1hi = pA1[1];
    f16x8 b1lo = pB1[0], b1hi = pB1[1];
    float v1   = val[e1s];
    float d1   = deg[i1];

    // Pin the schedule: nothing below may move above, no load may sink below.
    // Edge-0's loads are the oldest in the vmcnt queue -> its first use waits
    // on vmcnt(N_edge1_loads), leaving edge-1's gathers in flight under the
    // edge-0 MLP.
    __builtin_amdgcn_sched_barrier(0);

    // ---- edge 0 ----
    {
        float x[L2DIM];
        EDGE_X(x, a0lo, a0hi, b0lo, b0hi, v0, d0);
        float ex0;
        MLP_TAIL(x, ex0);
        eout[e0] = ex0;
        atomicAdd(&ssum[i0], ex0);
    }

    // ---- edge 1 ----
    if (has1) {
        float x[L2DIM];
        EDGE_X(x, a1lo, a1hi, b1lo, b1hi, v1, d1);
        float ex1;
        MLP_TAIL(x, ex1);
        eout[e1] = ex1;
        atomicAdd(&ssum[i1], ex1);
    }
}

// ============================================================================
// K3: out = ex / s[i], 4 edges/thread vectorized
// ============================================================================
__global__ void normalize(const int* __restrict__ ind_i, const float* __restrict__ ssum,
                          float* __restrict__ ex, int E) {
    int t = blockIdx.x * blockDim.x + threadIdx.x;
    int e = t * 4;
    if (e + 3 < E) {
        int4   ii = *reinterpret_cast<const int4*>(ind_i + e);
        float4 vv = *reinterpret_cast<const float4*>(ex + e);
        vv.x /= ssum[ii.x];
        vv.y /= ssum[ii.y];
        vv.z /= ssum[ii.z];
        vv.w /= ssum[ii.w];
        *reinterpret_cast<float4*>(ex + e) = vv;
    } else {
        for (; e < E; ++e) ex[e] = ex[e] / ssum[ind_i[e]];
    }
}

extern "C" void kernel_launch(void* const* d_in, const int* in_sizes, int n_in,
                              void* d_out, int out_size, void* d_ws, size_t ws_size,
                              hipStream_t stream) {
    const int*   Jt_ind = (const int*)  d_in[0];   // [2,E]
    const float* Jt_val = (const float*)d_in[1];   // [E]
    const float* f      = (const float*)d_in[2];   // [N,128]
    const float* W1 = (const float*)d_in[4];       // [256,16]
    const float* b1 = (const float*)d_in[5];       // [16]
    const float* W2 = (const float*)d_in[6];       // [17,17]
    const float* b2 = (const float*)d_in[7];       // [17]
    const float* Wc = (const float*)d_in[8];       // [17,1]
    const float* bc = (const float*)d_in[9];       // [1]

    const int E = in_sizes[1];
    const int N = in_sizes[2] / FDIM;
    float* out = (float*)d_out;                    // [E] fp32

    // workspace: deg[N] | ssum[N] (contiguous -> one memset) | A[N] | B[N]
    char* ws = (char*)d_ws;
    float* deg  = (float*)ws;  ws += (size_t)N * sizeof(float);
    float* ssum = (float*)ws;  ws += (size_t)N * sizeof(float);
    H16*   A    = (H16*)ws;    ws += (size_t)N * sizeof(H16);
    H16*   Bm   = (H16*)ws;    ws += (size_t)N * sizeof(H16);

    const int B256 = 256;
    const int nblk = (N + TRM - 1) / TRM;                   // node tiles (128 rows)
    const int E2   = (E + 1) / 2;                           // edge pairs
    const int eblk = (E2 + B256 - 1) / B256;                // 2 edges/thread
    const int qblk = ((E + 3) / 4 + B256 - 1) / B256;       // 4 edges/thread

    hipMemsetAsync(deg, 0, 2 * (size_t)N * sizeof(float), stream);
    node_transform<<<nblk, B256, 0, stream>>>(f, W1, b1, Jt_ind, Jt_val,
                                              A, Bm, deg, N, E);
    edge_mlp      <<<eblk, B256, 0, stream>>>(Jt_ind, Jt_val, A, Bm, deg,
                                              W2, b2, Wc, bc, out, ssum, E);
    normalize     <<<qblk, B256, 0, stream>>>(Jt_ind, ssum, out, E);
}

// Round 6
// 209.579 us; speedup vs baseline: 1.6878x; 1.0006x over previous
//
#include <hip/hip_runtime.h>
#include <hip/hip_fp16.h>
#include <math.h>

#define FDIM  128
#define L1OUT 16
#define L2DIM 17
#define TRM   64      // f-rows per block (R6: halved 128->64; grid was only
                      // 3.05 blocks/CU -- occupancy was GRID-limited, not LDS)
#define HSTR  136     // LDS tile row stride in halves (272 B: 2-way-only conflicts)

typedef _Float16 f16x8 __attribute__((ext_vector_type(8)));   // MFMA A/B frag (4 VGPR)
typedef float    f32x4 __attribute__((ext_vector_type(4)));   // MFMA C/D frag

// one 32-byte fp16 node row (16 halves); align 16 -> 2x global_load_dwordx4
struct __align__(16) H16 { __half2 h[8]; };

__device__ __forceinline__ float lrelu(float v) { return v >= 0.f ? v : 0.1f * v; }

// ============================================================================
// K1 (MFMA, LDS-staged): [A|B] = f @ W'.
// R5 fact: warm node_transform = 59.6us, VALU 2.4%, HBM 13%, Occ 25% --
// latency-bound with everything idle. Limiter by arithmetic: 782 blocks on
// 256 CUs = 3.05 blocks/CU (grid-limited occupancy; LDS allowed 4, VGPR=44
// allowed 8 waves/EU). R6 fix: TRM=64 -> 1563 blocks (~6.1/CU), 17.4KB LDS
// (8 blocks fit), each wave owns ONE 16-row M-subtile (si loop removed),
// half the per-block serial latency chain.
// R4 lesson (permanent): cooperative grid.sync K2/K3 fusion pushed ssum
// traffic through HBM on non-coherent XCD L2s: 176us vs 58+12 split. Deleted.
// Layouts (HW-verified per guide): A-frag A[m=lane&15][k=(lane>>4)*8+j];
// B-frag B[k=(lane>>4)*8+j][n=lane&15]; C/D col=lane&15, row=(lane>>4)*4+reg.
// + degree atomics folded in (deg zeroed by memsetAsync before this kernel).
// ============================================================================
__global__ void node_transform(
    const float* __restrict__ f, const float* __restrict__ W1,
    const float* __restrict__ b1,
    const int* __restrict__ ind_i, const float* __restrict__ val,
    H16* __restrict__ A, H16* __restrict__ B,
    float* __restrict__ deg, int N, int E)
{
    __shared__ __align__(16) _Float16 tile[TRM * HSTR];   // 17.4 KB

    const int t    = threadIdx.x;
    const int gtid = blockIdx.x * 256 + t;
    const int GT   = gridDim.x * 256;

    // ---- degree atomics (grid-stride, fire-and-forget) ----
    {
        const int E4 = E >> 2;
        for (int q = gtid; q < E4; q += GT) {
            int e = q << 2;
            int4   ii = *reinterpret_cast<const int4*>(ind_i + e);
            float4 vv = *reinterpret_cast<const float4*>(val + e);
            atomicAdd(&deg[ii.x], fabsf(vv.x));
            atomicAdd(&deg[ii.y], fabsf(vv.y));
            atomicAdd(&deg[ii.z], fabsf(vv.z));
            atomicAdd(&deg[ii.w], fabsf(vv.w));
        }
        if (gtid < (E & 3)) {
            int e = (E & ~3) + gtid;
            atomicAdd(&deg[ind_i[e]], fabsf(val[e]));
        }
    }

    const int lane = t & 63;
    const int wv   = t >> 6;          // wave 0..3 -> M-subtile wv
    const int n    = lane & 15;       // MFMA matrix-dim index (col)
    const int quad = lane >> 4;       // k-block / row-group selector

    // ---- load W' B-frags once per block: bfr[nt][ks], k = 32*ks + 8*quad + j
    f16x8 bfr[2][4];
#pragma unroll
    for (int nt = 0; nt < 2; ++nt)
#pragma unroll
        for (int ks = 0; ks < 4; ++ks) {
            f16x8 bf;
#pragma unroll
            for (int j = 0; j < 8; ++j) {
                int k = 32 * ks + 8 * quad + j;
                bf[j] = (_Float16)W1[(size_t)(nt * FDIM + k) * L1OUT + n];
            }
            bfr[nt][ks] = bf;
        }
    float b1v = b1[n];                // folded into nt=0 accumulator init

    // ---- stage 64 f-rows as fp16 into padded LDS tile (coalesced) ----
    const int base = blockIdx.x * TRM;
#pragma unroll
    for (int q = 0; q < 4; ++q) {
        int p  = t + 256 * q;         // half8-chunk index 0..1023
        int r  = p >> 4;              // 16 chunks per row
        int c8 = p & 15;              // chunk within row (8 halves)
        float4 lo = make_float4(0.f, 0.f, 0.f, 0.f);
        float4 hi = lo;
        if (base + r < N) {
            const float4* src = reinterpret_cast<const float4*>(
                f + (size_t)(base + r) * FDIM + c8 * 8);
            lo = src[0];
            hi = src[1];
        }
        f16x8 hx;
        hx[0] = (_Float16)lo.x; hx[1] = (_Float16)lo.y;
        hx[2] = (_Float16)lo.z; hx[3] = (_Float16)lo.w;
        hx[4] = (_Float16)hi.x; hx[5] = (_Float16)hi.y;
        hx[6] = (_Float16)hi.z; hx[7] = (_Float16)hi.w;
        *reinterpret_cast<f16x8*>(&tile[r * HSTR + c8 * 8]) = hx;
    }
    __syncthreads();

    // ---- compute: wave wv handles M-subtile wv (16 rows) ----
    {
        const int m0 = wv * 16;
        f32x4 acc0 = { b1v, b1v, b1v, b1v };      // A-cols + b1
        f32x4 acc1 = { 0.f, 0.f, 0.f, 0.f };      // B-cols
#pragma unroll
        for (int ks = 0; ks < 4; ++ks) {
            // A-frag: row m0+n, k = 32*ks + 8*quad .. +7  (one ds_read_b128)
            f16x8 af = *reinterpret_cast<const f16x8*>(
                &tile[(m0 + n) * HSTR + 32 * ks + 8 * quad]);
            acc0 = __builtin_amdgcn_mfma_f32_16x16x32_f16(af, bfr[0][ks], acc0, 0, 0, 0);
            acc1 = __builtin_amdgcn_mfma_f32_16x16x32_f16(af, bfr[1][ks], acc1, 0, 0, 0);
        }
        // epilogue: D col = n, rows = m0 + quad*4 + reg
#pragma unroll
        for (int reg = 0; reg < 4; ++reg) {
            int node = base + m0 + quad * 4 + reg;
            if (node < N) {
                reinterpret_cast<_Float16*>(A + node)[n] = (_Float16)acc0[reg];
                reinterpret_cast<_Float16*>(B + node)[n] = (_Float16)acc1[reg];
            }
        }
    }
}

// ============================================================================
// Shared MLP tail: x[17] -> L2 layer -> collapse -> exp. NO references/structs
// in the hot path (R1 lesson: addressable gather results -> alloca -> 672 MB
// scratch traffic). All indices compile-time; SROA keeps everything in VGPRs.
// ============================================================================
#define MLP_TAIL(X, EXOUT)                                                  \
    {                                                                       \
        float acc[L2DIM];                                                   \
        _Pragma("unroll")                                                   \
        for (int r = 0; r < L2DIM; ++r) acc[r] = b2s[r];                    \
        _Pragma("unroll")                                                   \
        for (int c = 0; c < L2DIM; ++c) {                                   \
            float xc = X[c];                                                \
            const float4* r4 = reinterpret_cast<const float4*>(&w2s[c * 20]); \
            float4 w0 = r4[0], w1v = r4[1], w2v = r4[2], w3 = r4[3];        \
            float  w16 = w2s[c * 20 + 16];                                  \
            acc[0]  += xc * w0.x;  acc[1]  += xc * w0.y;                    \
            acc[2]  += xc * w0.z;  acc[3]  += xc * w0.w;                    \
            acc[4]  += xc * w1v.x; acc[5]  += xc * w1v.y;                   \
            acc[6]  += xc * w1v.z; acc[7]  += xc * w1v.w;                   \
            acc[8]  += xc * w2v.x; acc[9]  += xc * w2v.y;                   \
            acc[10] += xc * w2v.z; acc[11] += xc * w2v.w;                   \
            acc[12] += xc * w3.x;  acc[13] += xc * w3.y;                    \
            acc[14] += xc * w3.z;  acc[15] += xc * w3.w;                    \
            acc[16] += xc * w16;                                            \
        }                                                                   \
        float ev = bc0s;                                                    \
        _Pragma("unroll")                                                   \
        for (int r = 0; r < L2DIM; ++r) ev += lrelu(acc[r]) * wcs[r];       \
        EXOUT = __expf(ev);                                                 \
    }

#define EDGE_X(X, ALO, AHI, BLO, BHI, V, D)                                 \
    _Pragma("unroll")                                                       \
    for (int k = 0; k < 8; ++k) {                                           \
        X[k]     = lrelu((float)ALO[k] + (float)BLO[k]);                    \
        X[k + 8] = lrelu((float)AHI[k] + (float)BHI[k]);                    \
    }                                                                       \
    X[L1OUT] = fabsf(V) / D;

// ============================================================================
// K2: per-edge MLP -> exp -> segment-sum. TWO edges per thread (e, e+E/2).
// R5 finding: sched_barrier(0) alone did NOT batch the loads -- VGPR stayed
// 64, meaning the allocator reused edge-1's destination regs for edge-0's
// compute scratch, and the implied s_waitcnt before reuse re-serialized the
// pipeline. R6 fix: asm volatile "+v" reads on ALL 12 gathered values force
// them live simultaneously at one point -> all loads issue as one batch and
// complete under ONE combined latency (~450cy) instead of two sequential
// ones. Verification: VGPR must rise to ~96-112; if it stays 64 the
// constraint was folded and this lever is conclusively dead.
// R1 lesson: no references/structs/lambdas on gather results (alloca ->
// scratch). Weights in LDS (stride-20 rows). Softmax max-pass removed:
// identical ratios; |e_val| <~ 15 (fp32-safe).
// ============================================================================
__global__ __launch_bounds__(256, 4) void edge_mlp(
    const int* __restrict__ ind, const float* __restrict__ val,
    const H16* __restrict__ A, const H16* __restrict__ B,
    const float* __restrict__ deg,
    const float* __restrict__ W2, const float* __restrict__ b2,
    const float* __restrict__ Wc, const float* __restrict__ bc,
    float* __restrict__ eout, float* __restrict__ ssum, int E)
{
    __shared__ float w2s[L2DIM * 20];   // row c at w2s[c*20], 16B-aligned
    __shared__ float b2s[L2DIM];
    __shared__ float wcs[L2DIM];
    __shared__ float bc0s;

    const int t = threadIdx.x;
    for (int idx = t; idx < L2DIM * L2DIM; idx += 256) {
        int c = idx / L2DIM, r = idx - c * L2DIM;
        w2s[c * 20 + r] = W2[idx];
    }
    if (t < L2DIM) b2s[t] = b2[t];
    if (t < L2DIM) wcs[t] = Wc[t];
    if (t == 0)    bc0s   = bc[0];
    __syncthreads();

    const int E2 = (E + 1) >> 1;          // pair stride
    const int p  = blockIdx.x * 256 + t;
    if (p >= E2) return;

    const int  e0   = p;
    const int  e1   = p + E2;
    const bool has1 = (e1 < E);
    const int  e1s  = has1 ? e1 : e0;     // safe clone address for tail

    // ---- issue the full load pipeline for both edges up front ----
    int i0 = ind[e0];   int j0 = ind[E + e0];
    int i1 = ind[e1s];  int j1 = ind[E + e1s];

    const f16x8* pA0 = reinterpret_cast<const f16x8*>(A + i0);
    const f16x8* pB0 = reinterpret_cast<const f16x8*>(B + j0);
    const f16x8* pA1 = reinterpret_cast<const f16x8*>(A + i1);
    const f16x8* pB1 = reinterpret_cast<const f16x8*>(B + j1);

    f16x8 a0lo = pA0[0], a0hi = pA0[1];   // 2x global_load_dwordx4 each
    f16x8 b0lo = pB0[0], b0hi = pB0[1];
    float v0   = val[e0];
    float d0   = deg[i0];
    f16x8 a1lo = pA1[0], a1hi = pA1[1];
    f16x8 b1lo = pB1[0], b1hi = pB1[1];
    float v1   = val[e1s];
    float d1   = deg[i1];

    // Force ALL gathered values live at this point: every load must have
    // issued (batched) and completed before any compute. One combined
    // memory-latency wait instead of two sequential ones.
    asm volatile("" : "+v"(a0lo), "+v"(a0hi), "+v"(b0lo), "+v"(b0hi),
                      "+v"(a1lo), "+v"(a1hi), "+v"(b1lo), "+v"(b1hi),
                      "+v"(v0), "+v"(d0), "+v"(v1), "+v"(d1));

    // ---- edge 0 ----
    {
        float x[L2DIM];
        EDGE_X(x, a0lo, a0hi, b0lo, b0hi, v0, d0);
        float ex0;
        MLP_TAIL(x, ex0);
        eout[e0] = ex0;
        atomicAdd(&ssum[i0], ex0);
    }

    // ---- edge 1 ----
    if (has1) {
        float x[L2DIM];
        EDGE_X(x, a1lo, a1hi, b1lo, b1hi, v1, d1);
        float ex1;
        MLP_TAIL(x, ex1);
        eout[e1] = ex1;
        atomicAdd(&ssum[i1], ex1);
    }
}

// ============================================================================
// K3: out = ex / s[i], 4 edges/thread vectorized
// ============================================================================
__global__ void normalize(const int* __restrict__ ind_i, const float* __restrict__ ssum,
                          float* __restrict__ ex, int E) {
    int t = blockIdx.x * blockDim.x + threadIdx.x;
    int e = t * 4;
    if (e + 3 < E) {
        int4   ii = *reinterpret_cast<const int4*>(ind_i + e);
        float4 vv = *reinterpret_cast<const float4*>(ex + e);
        vv.x /= ssum[ii.x];
        vv.y /= ssum[ii.y];
        vv.z /= ssum[ii.z];
        vv.w /= ssum[ii.w];
        *reinterpret_cast<float4*>(ex + e) = vv;
    } else {
        for (; e < E; ++e) ex[e] = ex[e] / ssum[ind_i[e]];
    }
}

extern "C" void kernel_launch(void* const* d_in, const int* in_sizes, int n_in,
                              void* d_out, int out_size, void* d_ws, size_t ws_size,
                              hipStream_t stream) {
    const int*   Jt_ind = (const int*)  d_in[0];   // [2,E]
    const float* Jt_val = (const float*)d_in[1];   // [E]
    const float* f      = (const float*)d_in[2];   // [N,128]
    const float* W1 = (const float*)d_in[4];       // [256,16]
    const float* b1 = (const float*)d_in[5];       // [16]
    const float* W2 = (const float*)d_in[6];       // [17,17]
    const float* b2 = (const float*)d_in[7];       // [17]
    const float* Wc = (const float*)d_in[8];       // [17,1]
    const float* bc = (const float*)d_in[9];       // [1]

    const int E = in_sizes[1];
    const int N = in_sizes[2] / FDIM;
    float* out = (float*)d_out;                    // [E] fp32

    // workspace: deg[N] | ssum[N] (contiguous -> one memset) | A[N] | B[N]
    char* ws = (char*)d_ws;
    float* deg  = (float*)ws;  ws += (size_t)N * sizeof(float);
    float* ssum = (float*)ws;  ws += (size_t)N * sizeof(float);
    H16*   A    = (H16*)ws;    ws += (size_t)N * sizeof(H16);
    H16*   Bm   = (H16*)ws;    ws += (size_t)N * sizeof(H16);

    const int B256 = 256;
    const int nblk = (N + TRM - 1) / TRM;                   // node tiles (64 rows)
    const int E2   = (E + 1) / 2;                           // edge pairs
    const int eblk = (E2 + B256 - 1) / B256;                // 2 edges/thread
    const int qblk = ((E + 3) / 4 + B256 - 1) / B256;       // 4 edges/thread

    hipMemsetAsync(deg, 0, 2 * (size_t)N * sizeof(float), stream);
    node_transform<<<nblk, B256, 0, stream>>>(f, W1, b1, Jt_ind, Jt_val,
                                              A, Bm, deg, N, E);
    edge_mlp      <<<eblk, B256, 0, stream>>>(Jt_ind, Jt_val, A, Bm, deg,
                                              W2, b2, Wc, bc, out, ssum, E);
    normalize     <<<qblk, B256, 0, stream>>>(Jt_ind, ssum, out, E);
}